// Round 5
// baseline (493.890 us; speedup 1.0000x reference)
//
#include <hip/hip_runtime.h>
#include <hip/hip_bf16.h>

#define T_TOK 8192
#define HDIM 1024
#define FDIM 2048
#define NEXP 8
#define NASSIGN (T_TOK * 2)
#define ROWCAP (NASSIGN + 256)  // packed rows + tail-tile slack
#define NHB 64                  // hist/scatter blocks
#define MAXT2 72                // max 256-row M-tiles: 16384/256 + 8

typedef __bf16 bf16;
typedef __bf16 bf16x4 __attribute__((ext_vector_type(4)));
typedef __bf16 bf16x8 __attribute__((ext_vector_type(8)));
typedef float f32x4 __attribute__((ext_vector_type(4)));

// async global->LDS, 16B per lane; LDS dest = wave-uniform base + lane*16
__device__ __forceinline__ void gload_lds16(const void* g, void* l) {
    __builtin_amdgcn_global_load_lds(
        (const __attribute__((address_space(1))) void*)(uintptr_t)g,
        (__attribute__((address_space(3))) void*)(uintptr_t)l,
        16, 0, 0);
}

// ---------------- transpose + fp32->bf16: in [E][R][C] fp32 -> out [E][C][R] bf16 ----------------
__global__ __launch_bounds__(256) void transpose_to_bf16(
    const float* __restrict__ in, bf16* __restrict__ out, int R, int C) {
    __shared__ float tile[64][68];
    int e = blockIdx.z;
    const float* inp = in + (size_t)e * R * C;
    bf16* outp = out + (size_t)e * R * C;
    int c0 = blockIdx.x * 64, r0 = blockIdx.y * 64;
    int tid = threadIdx.x;
    int tx = tid & 15, ty = tid >> 4;
#pragma unroll
    for (int i = 0; i < 4; i++) {
        int row = ty + i * 16;
        float4 v = *(const float4*)&inp[(size_t)(r0 + row) * C + c0 + tx * 4];
        *(float4*)&tile[row][tx * 4] = v;
    }
    __syncthreads();
#pragma unroll
    for (int i = 0; i < 2; i++) {
        int idx = tid + i * 256;
        int c = idx >> 3, seg = idx & 7;
        bf16x8 v;
#pragma unroll
        for (int j = 0; j < 8; j++) v[j] = (bf16)tile[seg * 8 + j][c];
        *(bf16x8*)&outp[(size_t)(c0 + c) * R + r0 + seg * 8] = v;
    }
}

// ---------------- phase A: per-token top-2 + gates (NO atomics) ----------------
__global__ __launch_bounds__(256) void router_kernel(
    const float* __restrict__ x, const float* __restrict__ rw,
    const float* __restrict__ rb, int* __restrict__ expert_pair,
    float2* __restrict__ gate_pair) {
    __shared__ float rwT[NEXP][HDIM];
    __shared__ float rbs[NEXP];
    int tid = threadIdx.x;
    for (int i = tid; i < HDIM * NEXP / 4; i += 256) {
        float4 v = ((const float4*)rw)[i];
        int h = i >> 1, e0 = (i & 1) * 4;
        rwT[e0 + 0][h] = v.x;
        rwT[e0 + 1][h] = v.y;
        rwT[e0 + 2][h] = v.z;
        rwT[e0 + 3][h] = v.w;
    }
    if (tid < NEXP) rbs[tid] = rb[tid];
    __syncthreads();
    int wave = tid >> 6, lane = tid & 63;
    int tbase = blockIdx.x * 32 + wave * 8;

    for (int tk = 0; tk < 8; tk++) {
        int t = tbase + tk;
        const float4* xt = (const float4*)(x + (size_t)t * HDIM);
        float p[NEXP];
#pragma unroll
        for (int e = 0; e < NEXP; e++) p[e] = 0.f;
#pragma unroll
        for (int it = 0; it < 4; it++) {
            float4 v = xt[it * 64 + lane];
            int h = (it * 64 + lane) * 4;
#pragma unroll
            for (int e = 0; e < NEXP; e++) {
                float4 wv = *(const float4*)&rwT[e][h];
                p[e] += v.x * wv.x + v.y * wv.y + v.z * wv.z + v.w * wv.w;
            }
        }
#pragma unroll
        for (int off = 32; off >= 1; off >>= 1) {
#pragma unroll
            for (int e = 0; e < NEXP; e++) p[e] += __shfl_xor(p[e], off, 64);
        }
        if (lane == 0) {
            float lg[NEXP];
#pragma unroll
            for (int e = 0; e < NEXP; e++) lg[e] = p[e] + rbs[e];
            int e0 = 0;
#pragma unroll
            for (int e = 1; e < NEXP; e++)
                if (lg[e] > lg[e0]) e0 = e;
            int e1 = -1;
#pragma unroll
            for (int e = 0; e < NEXP; e++) {
                if (e == e0) continue;
                if (e1 < 0 || lg[e] > lg[e1]) e1 = e;
            }
            float z = expf(lg[e1] - lg[e0]);
            expert_pair[t] = e0 | (e1 << 16);
            gate_pair[t] = make_float2(1.f / (1.f + z), z / (1.f + z));
        }
    }
}

// ---------------- phase B: per-block expert histogram via ballots ----------------
__global__ __launch_bounds__(256) void hist_kernel(
    const int* __restrict__ expert_pair, int* __restrict__ hist) {
    int tid = threadIdx.x;
    int wave = tid >> 6, lane = tid & 63;
    int a = blockIdx.x * 256 + tid;
    int t = a >> 1, j = a & 1;
    int e = (expert_pair[t] >> (16 * j)) & 0xffff;
    __shared__ int wcnt[4][NEXP];
#pragma unroll
    for (int ee = 0; ee < NEXP; ee++) {
        unsigned long long m = __ballot(e == ee);
        if (lane == 0) wcnt[wave][ee] = __popcll(m);
    }
    __syncthreads();
    if (tid < NEXP)
        hist[blockIdx.x * NEXP + tid] =
            wcnt[0][tid] + wcnt[1][tid] + wcnt[2][tid] + wcnt[3][tid];
}

// ---------------- phase C: scan -> cnt, offs, per-block starts, tile tables ----------------
__global__ __launch_bounds__(256) void scan_kernel(
    const int* __restrict__ hist, int* __restrict__ start,
    int* __restrict__ cnt, int* __restrict__ offs,
    int* __restrict__ tile_e2, int* __restrict__ tile_m2,
    int* __restrict__ ntiles2) {
    __shared__ int h[NHB * NEXP];
    __shared__ int tot[NEXP];
    __shared__ int offsh[NEXP];
    int tid = threadIdx.x;
    for (int i = tid; i < NHB * NEXP; i += 256) h[i] = hist[i];
    __syncthreads();
    if (tid < NEXP) {
        int s = 0;
        for (int b = 0; b < NHB; b++) s += h[b * NEXP + tid];
        tot[tid] = s;
        cnt[tid] = s;
    }
    __syncthreads();
    if (tid == 0) {
        int o = 0;
        for (int e = 0; e < NEXP; e++) {
            offsh[e] = o;
            offs[e] = o;
            o += tot[e];
        }
        // 256-row tile table (both GEMMs)
        int idx2 = 0;
        for (int e = 0; e < NEXP; e++) {
            int nt = (tot[e] + 255) >> 8;
            for (int m = 0; m < nt; m++) {
                tile_e2[idx2] = e;
                tile_m2[idx2] = m;
                idx2++;
            }
        }
        ntiles2[0] = idx2;
    }
    __syncthreads();
    if (tid < NEXP) {
        int run = offsh[tid];
        for (int b = 0; b < NHB; b++) {
            start[b * NEXP + tid] = run;
            run += h[b * NEXP + tid];
        }
    }
}

// ---------------- phase D: deterministic scatter via ballot ranks ----------------
__global__ __launch_bounds__(256) void scatter_kernel(
    const int* __restrict__ expert_pair, const float2* __restrict__ gate_pair,
    const int* __restrict__ start, int* __restrict__ perm,
    float* __restrict__ gatebuf, int* __restrict__ rowbuf) {
    int tid = threadIdx.x;
    int wave = tid >> 6, lane = tid & 63;
    int a = blockIdx.x * 256 + tid;
    int t = a >> 1, j = a & 1;
    int e = (expert_pair[t] >> (16 * j)) & 0xffff;
    float2 gp = gate_pair[t];
    float g = j ? gp.y : gp.x;
    __shared__ int wcnt[4][NEXP];
    int rankw = 0;
    unsigned long long below = (1ull << lane) - 1ull;
#pragma unroll
    for (int ee = 0; ee < NEXP; ee++) {
        unsigned long long m = __ballot(e == ee);
        if (lane == 0) wcnt[wave][ee] = __popcll(m);
        if (ee == e) rankw = __popcll(m & below);
    }
    __syncthreads();
    int cross = 0;
    for (int w = 0; w < wave; w++) cross += wcnt[w][e];
    int pos = start[blockIdx.x * NEXP + e] + cross + rankw;
    perm[pos] = t;
    gatebuf[pos] = g;
    rowbuf[a] = pos;
}

// ---------------- pack: gather x rows into packed order, fp32 -> bf16 ----------------
__global__ __launch_bounds__(256) void pack_kernel(
    const float* __restrict__ x, const int* __restrict__ perm,
    bf16* __restrict__ xg) {
    int r0 = blockIdx.x * 16;
    int wave = threadIdx.x >> 6, lane = threadIdx.x & 63;
#pragma unroll
    for (int i = 0; i < 4; i++) {
        int row = r0 + wave * 4 + i;
        int tok = perm[row];
        const float* src = x + (size_t)tok * HDIM;
        bf16* dst = xg + (size_t)row * HDIM;
#pragma unroll
        for (int it = 0; it < 4; it++) {
            int c = (it * 64 + lane) * 4;
            float4 v = *(const float4*)&src[c];
            bf16x4 b = {(bf16)v.x, (bf16)v.y, (bf16)v.z, (bf16)v.w};
            *(bf16x4*)&dst[c] = b;
        }
    }
}

// ================= grouped GEMM: BM=256 x BN=128, BK=32, 4 waves, wave tile 128x64 ====
// R4 skeleton (tri-buffer, counted vmcnt, pre-swizzled src + swizzled read) with FAT
// wave tiles: per K-step a wave reads 12 ds_read_b128 and issues 32 MFMA (0.023 LDS
// B/FLOP vs R4's 0.038) so the matrix pipe, not LDS fragment traffic, is the limiter.
// 256 thr/block, ~210 VGPR, 72 KB LDS -> 2 blocks/CU; co-resident block hides the
// per-block serial ds_read->MFMA chain. Staging: 6 gloads/thread/K-tile; steady-state
// vmcnt(12) = 2 tiles in flight (distance-2 tri-buffer, same ledger as R4 scaled x2).
template <bool RELU, bool GATE, int K, int N>
__global__ __launch_bounds__(256, 2) void moe_gemm_p(
    const bf16* __restrict__ A, const bf16* __restrict__ B,
    const float* __restrict__ bias, const float* __restrict__ gates,
    bf16* __restrict__ out, const int* __restrict__ cnt,
    const int* __restrict__ offs, const int* __restrict__ tile_e2,
    const int* __restrict__ tile_m2, const int* __restrict__ ntiles2) {
    constexpr int NT = N / 128;
    constexpr int nk = K / 32;
    int ntl = ntiles2[0];
    int nact = ntl * NT;
    int f = blockIdx.x;
    if (f >= nact) return;
    // bijective chunked XCD swizzle over the active range (m204)
    int q8 = nact >> 3, r8 = nact & 7;
    int xcd = f & 7, rest = f >> 3;
    int wg = (xcd < r8) ? (xcd * (q8 + 1) + rest)
                        : (r8 * (q8 + 1) + (xcd - r8) * q8 + rest);
    int tile = wg / NT, ncol = wg - tile * NT;
    int e = tile_e2[tile];
    int n_cnt = cnt[e];
    int off_e = offs[e];
    int m0 = tile_m2[tile] * 256;
    int n0 = ncol * 128;

    __shared__ bf16 As[3][256][32];  // 48 KB
    __shared__ bf16 Bs[3][128][32];  // 24 KB

    int tid = threadIdx.x;
    int lane = tid & 63;
    int wave = tid >> 6;  // 0..3
    int wm = wave & 1;    // A rows wm*128..+127
    int wn = wave >> 1;   // B cols wn*64..+63
    int quad = lane >> 4, l16 = lane & 15;
    int rsw = (quad ^ ((l16 >> 1) & 3)) * 8;  // swizzled 16B seg (elems)

    const bf16* Ae = A + (size_t)off_e * K;
    const bf16* Be = B + (size_t)e * (size_t)N * K;

    // staging: chunk c (16B) covers LDS row c>>2, seg c&3; thread tid handles
    // chunks {tid, tid+256, tid+512, tid+768} of A (rows tid>>2 + 64j) and
    // {tid, tid+256} of B. Source seg pre-swizzled by (row>>1)&3 == (tid>>3)&3.
    int r0s = tid >> 2;  // 0..63
    int segs = (tid & 3) ^ ((tid >> 3) & 3);
    const bf16* agA = Ae + (size_t)(m0 + r0s) * K + segs * 8;
    const bf16* bgB = Be + (size_t)(n0 + r0s) * K + segs * 8;

    auto STG = [&](int buf, int kt) {
        bf16* Ab = (bf16*)As + (size_t)buf * (256 * 32);
        bf16* Bb = (bf16*)Bs + (size_t)buf * (128 * 32);
#pragma unroll
        for (int j = 0; j < 4; j++)
            gload_lds16(agA + (size_t)(j * 64) * K + (size_t)kt * 32,
                        Ab + wave * 512 + j * 2048);
#pragma unroll
        for (int j = 0; j < 2; j++)
            gload_lds16(bgB + (size_t)(j * 64) * K + (size_t)kt * 32,
                        Bb + wave * 512 + j * 2048);
    };

    f32x4 acc[8][4];
#pragma unroll
    for (int i = 0; i < 8; i++)
#pragma unroll
        for (int j = 0; j < 4; j++) acc[i][j] = f32x4{0.f, 0.f, 0.f, 0.f};

    // prologue: stage tiles 0,1 (6 loads each)
    STG(0, 0);
    STG(1, 1);

    int b = 0, bs = 2;  // compute buf, stage buf (t+2)%3
    for (int t = 0; t < nk; t++) {
        if (t + 2 < nk) {
            STG(bs, t + 2);
            asm volatile("s_waitcnt vmcnt(12)" ::: "memory");  // tile t landed
        } else if (t + 2 == nk) {
            asm volatile("s_waitcnt vmcnt(6)" ::: "memory");
        } else {
            asm volatile("s_waitcnt vmcnt(0)" ::: "memory");
        }
        asm volatile("s_barrier" ::: "memory");

        const bf16* Ab = (const bf16*)As + (size_t)b * (256 * 32);
        const bf16* Bb = (const bf16*)Bs + (size_t)b * (128 * 32);
        bf16x8 bfv[4];
#pragma unroll
        for (int nj = 0; nj < 4; nj++)
            bfv[nj] = *(const bf16x8*)(Bb + (wn * 64 + nj * 16 + l16) * 32 + rsw);
        bf16x8 af[8];
#pragma unroll
        for (int mi = 0; mi < 8; mi++)
            af[mi] = *(const bf16x8*)(Ab + (wm * 128 + mi * 16 + l16) * 32 + rsw);
        __builtin_amdgcn_s_setprio(1);
#pragma unroll
        for (int mi = 0; mi < 8; mi++)
#pragma unroll
            for (int nj = 0; nj < 4; nj++)
                acc[mi][nj] = __builtin_amdgcn_mfma_f32_16x16x32_bf16(
                    af[mi], bfv[nj], acc[mi][nj], 0, 0, 0);
        __builtin_amdgcn_s_setprio(0);
        asm volatile("s_barrier" ::: "memory");

        b = (b == 2) ? 0 : b + 1;
        bs = (bs == 2) ? 0 : bs + 1;
    }

#pragma unroll
    for (int mi = 0; mi < 8; mi++)
#pragma unroll
        for (int nj = 0; nj < 4; nj++)
#pragma unroll
            for (int r = 0; r < 4; r++) {
                int m = m0 + wm * 128 + mi * 16 + quad * 4 + r;
                if (m < n_cnt) {
                    int n = n0 + wn * 64 + nj * 16 + l16;
                    float v = acc[mi][nj][r] + bias[e * N + n];
                    if (RELU) v = v > 0.f ? v : 0.f;
                    if (GATE) v *= gates[off_e + m];
                    out[(size_t)(off_e + m) * N + n] = (bf16)v;
                }
            }
}

// ---------------- combine ----------------
__global__ __launch_bounds__(256) void combine_kernel(
    const bf16* __restrict__ eout, const int* __restrict__ rowbuf,
    float* __restrict__ out) {
    int t = blockIdx.x;
    int r0 = rowbuf[2 * t], r1 = rowbuf[2 * t + 1];
    const bf16* p0 = eout + (size_t)r0 * HDIM;
    const bf16* p1 = eout + (size_t)r1 * HDIM;
    float* o = out + (size_t)t * HDIM;
    int n = threadIdx.x * 4;
    bf16x4 a = *(const bf16x4*)&p0[n];
    bf16x4 b = *(const bf16x4*)&p1[n];
    float4 v = {(float)a[0] + (float)b[0], (float)a[1] + (float)b[1],
                (float)a[2] + (float)b[2], (float)a[3] + (float)b[3]};
    *(float4*)&o[n] = v;
}

extern "C" void kernel_launch(void* const* d_in, const int* in_sizes, int n_in,
                              void* d_out, int out_size, void* d_ws, size_t ws_size,
                              hipStream_t stream) {
    const float* x = (const float*)d_in[0];
    const float* rw = (const float*)d_in[1];
    const float* rb = (const float*)d_in[2];
    const float* w1 = (const float*)d_in[3];
    const float* b1 = (const float*)d_in[4];
    const float* w2 = (const float*)d_in[5];
    const float* b2 = (const float*)d_in[6];
    float* out = (float*)d_out;

    char* ws = (char*)d_ws;
    size_t o = 0;
    auto alloc = [&](size_t bytes) {
        char* p = ws + o;
        o += (bytes + 255) & ~(size_t)255;
        return p;
    };
    bf16* w1t = (bf16*)alloc((size_t)NEXP * FDIM * HDIM * 2);
    bf16* w2t = (bf16*)alloc((size_t)NEXP * HDIM * FDIM * 2);
    bf16* hbuf = (bf16*)alloc((size_t)ROWCAP * FDIM * 2);
    bf16* xg = (bf16*)alloc((size_t)ROWCAP * HDIM * 2);  // aliased: xg (gemm1 A) then eout (gemm2 out)
    bf16* eout = xg;
    int* expert_pair = (int*)alloc((size_t)T_TOK * 4);
    float2* gate_pair = (float2*)alloc((size_t)T_TOK * 8);
    int* hist = (int*)alloc((size_t)NHB * NEXP * 4);
    int* start = (int*)alloc((size_t)NHB * NEXP * 4);
    int* perm = (int*)alloc((size_t)NASSIGN * 4);
    float* gatebuf = (float*)alloc((size_t)NASSIGN * 4);
    int* rowbuf = (int*)alloc((size_t)NASSIGN * 4);
    int* cnt = (int*)alloc(256);
    int* offs = (int*)alloc(256);
    int* tile_e2 = (int*)alloc((size_t)MAXT2 * 4);
    int* tile_m2 = (int*)alloc((size_t)MAXT2 * 4);
    int* ntiles2 = (int*)alloc(256);

    transpose_to_bf16<<<dim3(FDIM / 64, HDIM / 64, NEXP), 256, 0, stream>>>(w1, w1t, HDIM, FDIM);
    transpose_to_bf16<<<dim3(HDIM / 64, FDIM / 64, NEXP), 256, 0, stream>>>(w2, w2t, FDIM, HDIM);
    router_kernel<<<T_TOK / 32, 256, 0, stream>>>(x, rw, rb, expert_pair, gate_pair);
    hist_kernel<<<NHB, 256, 0, stream>>>(expert_pair, hist);
    scan_kernel<<<1, 256, 0, stream>>>(hist, start, cnt, offs, tile_e2, tile_m2, ntiles2);
    scatter_kernel<<<NHB, 256, 0, stream>>>(expert_pair, gate_pair, start, perm, gatebuf, rowbuf);
    pack_kernel<<<NASSIGN / 16, 256, 0, stream>>>(x, perm, xg);
    moe_gemm_p<true, false, HDIM, FDIM><<<dim3(MAXT2 * (FDIM / 128)), 256, 0, stream>>>(
        xg, w1t, b1, nullptr, hbuf, cnt, offs, tile_e2, tile_m2, ntiles2);
    moe_gemm_p<false, true, FDIM, HDIM><<<dim3(MAXT2 * (HDIM / 128)), 256, 0, stream>>>(
        hbuf, w2t, b2, gatebuf, eout, cnt, offs, tile_e2, tile_m2, ntiles2);
    combine_kernel<<<T_TOK, 256, 0, stream>>>(eout, rowbuf, out);
}

// Round 6
// 449.063 us; speedup vs baseline: 1.0998x; 1.0998x over previous
//
#include <hip/hip_runtime.h>
#include <hip/hip_bf16.h>

#define T_TOK 8192
#define HDIM 1024
#define FDIM 2048
#define NEXP 8
#define NASSIGN (T_TOK * 2)
#define ROWCAP (NASSIGN + 256)  // packed rows + tail-tile slack
#define NHB 256                 // router/hist blocks (32 tokens each)
#define MAXT2 72                // max 256-row M-tiles: 16384/256 + 8

typedef __bf16 bf16;
typedef __bf16 bf16x4 __attribute__((ext_vector_type(4)));
typedef __bf16 bf16x8 __attribute__((ext_vector_type(8)));
typedef float f32x4 __attribute__((ext_vector_type(4)));

// async global->LDS, 16B per lane; LDS dest = wave-uniform base + lane*16,
// global SOURCE is per-lane (enables gather-staging).
__device__ __forceinline__ void gload_lds16(const void* g, void* l) {
    __builtin_amdgcn_global_load_lds(
        (const __attribute__((address_space(1))) void*)(uintptr_t)g,
        (__attribute__((address_space(3))) void*)(uintptr_t)l,
        16, 0, 0);
}

// ---------------- transpose + fp32->bf16: in [E][R][C] fp32 -> out [E][C][R] bf16 ----------------
__global__ __launch_bounds__(256) void transpose_to_bf16(
    const float* __restrict__ in, bf16* __restrict__ out, int R, int C) {
    __shared__ float tile[64][68];
    int e = blockIdx.z;
    const float* inp = in + (size_t)e * R * C;
    bf16* outp = out + (size_t)e * R * C;
    int c0 = blockIdx.x * 64, r0 = blockIdx.y * 64;
    int tid = threadIdx.x;
    int tx = tid & 15, ty = tid >> 4;
#pragma unroll
    for (int i = 0; i < 4; i++) {
        int row = ty + i * 16;
        float4 v = *(const float4*)&inp[(size_t)(r0 + row) * C + c0 + tx * 4];
        *(float4*)&tile[row][tx * 4] = v;
    }
    __syncthreads();
#pragma unroll
    for (int i = 0; i < 2; i++) {
        int idx = tid + i * 256;
        int c = idx >> 3, seg = idx & 7;
        bf16x8 v;
#pragma unroll
        for (int j = 0; j < 8; j++) v[j] = (bf16)tile[seg * 8 + j][c];
        *(bf16x8*)&outp[(size_t)(c0 + c) * R + r0 + seg * 8] = v;
    }
}

// ---------------- router: top-2 + gates + fused x->bf16 copy + fused per-block hist ------
__global__ __launch_bounds__(256) void router_kernel(
    const float* __restrict__ x, const float* __restrict__ rw,
    const float* __restrict__ rb, int* __restrict__ expert_pair,
    float2* __restrict__ gate_pair, bf16* __restrict__ xb,
    int* __restrict__ hist) {
    __shared__ float rwT[NEXP][HDIM];
    __shared__ float rbs[NEXP];
    __shared__ int sh_pair[32];
    int tid = threadIdx.x;
    for (int i = tid; i < HDIM * NEXP / 4; i += 256) {
        float4 v = ((const float4*)rw)[i];
        int h = i >> 1, e0 = (i & 1) * 4;
        rwT[e0 + 0][h] = v.x;
        rwT[e0 + 1][h] = v.y;
        rwT[e0 + 2][h] = v.z;
        rwT[e0 + 3][h] = v.w;
    }
    if (tid < NEXP) rbs[tid] = rb[tid];
    __syncthreads();
    int wave = tid >> 6, lane = tid & 63;
    int tbase = blockIdx.x * 32 + wave * 8;

    for (int tk = 0; tk < 8; tk++) {
        int t = tbase + tk;
        const float4* xt = (const float4*)(x + (size_t)t * HDIM);
        float p[NEXP];
#pragma unroll
        for (int e = 0; e < NEXP; e++) p[e] = 0.f;
#pragma unroll
        for (int it = 0; it < 4; it++) {
            float4 v = xt[it * 64 + lane];
            // fused fp32 -> bf16 copy (unpermuted); GEMM1 gathers from xb
            bf16x4 bv = {(bf16)v.x, (bf16)v.y, (bf16)v.z, (bf16)v.w};
            *(bf16x4*)&xb[(size_t)t * HDIM + (it * 64 + lane) * 4] = bv;
            int h = (it * 64 + lane) * 4;
#pragma unroll
            for (int e = 0; e < NEXP; e++) {
                float4 wv = *(const float4*)&rwT[e][h];
                p[e] += v.x * wv.x + v.y * wv.y + v.z * wv.z + v.w * wv.w;
            }
        }
#pragma unroll
        for (int off = 32; off >= 1; off >>= 1) {
#pragma unroll
            for (int e = 0; e < NEXP; e++) p[e] += __shfl_xor(p[e], off, 64);
        }
        if (lane == 0) {
            float lg[NEXP];
#pragma unroll
            for (int e = 0; e < NEXP; e++) lg[e] = p[e] + rbs[e];
            int e0 = 0;
#pragma unroll
            for (int e = 1; e < NEXP; e++)
                if (lg[e] > lg[e0]) e0 = e;
            int e1 = -1;
#pragma unroll
            for (int e = 0; e < NEXP; e++) {
                if (e == e0) continue;
                if (e1 < 0 || lg[e] > lg[e1]) e1 = e;
            }
            float z = expf(lg[e1] - lg[e0]);
            int pair = e0 | (e1 << 16);
            expert_pair[t] = pair;
            sh_pair[wave * 8 + tk] = pair;
            gate_pair[t] = make_float2(1.f / (1.f + z), z / (1.f + z));
        }
    }
    __syncthreads();
    // fused per-block histogram: 64 assignments, one wave
    if (wave == 0) {
        int tl = lane >> 1, j = lane & 1;
        int e = (sh_pair[tl] >> (16 * j)) & 0xffff;
#pragma unroll
        for (int ee = 0; ee < NEXP; ee++) {
            unsigned long long m = __ballot(e == ee);
            if (lane == ee) hist[blockIdx.x * NEXP + ee] = __popcll(m);
        }
    }
}

// ---------------- scan -> cnt, offs, per-router-block starts, 256-row tile table --------
__global__ __launch_bounds__(256) void scan_kernel(
    const int* __restrict__ hist, int* __restrict__ start,
    int* __restrict__ cnt, int* __restrict__ offs,
    int* __restrict__ tile_e2, int* __restrict__ tile_m2,
    int* __restrict__ ntiles2) {
    __shared__ int h[NHB * NEXP];
    __shared__ int tot[NEXP];
    __shared__ int offsh[NEXP];
    int tid = threadIdx.x;
    for (int i = tid; i < NHB * NEXP; i += 256) h[i] = hist[i];
    __syncthreads();
    if (tid < NEXP) {
        int s = 0;
        for (int b = 0; b < NHB; b++) s += h[b * NEXP + tid];
        tot[tid] = s;
        cnt[tid] = s;
    }
    __syncthreads();
    if (tid == 0) {
        int o = 0;
        for (int e = 0; e < NEXP; e++) {
            offsh[e] = o;
            offs[e] = o;
            o += tot[e];
        }
        int idx2 = 0;
        for (int e = 0; e < NEXP; e++) {
            int nt = (tot[e] + 255) >> 8;
            for (int m = 0; m < nt; m++) {
                tile_e2[idx2] = e;
                tile_m2[idx2] = m;
                idx2++;
            }
        }
        ntiles2[0] = idx2;
    }
    __syncthreads();
    if (tid < NEXP) {
        int run = offsh[tid];
        for (int b = 0; b < NHB; b++) {
            start[b * NEXP + tid] = run;
            run += h[b * NEXP + tid];
        }
    }
}

// ---------------- scatter: one wave per router-block (64 assignments) -------------------
__global__ __launch_bounds__(64) void scatter_kernel(
    const int* __restrict__ expert_pair, const float2* __restrict__ gate_pair,
    const int* __restrict__ start, int* __restrict__ perm,
    float* __restrict__ gatebuf, int* __restrict__ rowbuf) {
    int lane = threadIdx.x;
    int a = blockIdx.x * 64 + lane;
    int t = a >> 1, j = a & 1;
    int e = (expert_pair[t] >> (16 * j)) & 0xffff;
    float2 gp = gate_pair[t];
    float g = j ? gp.y : gp.x;
    int rank = 0;
    unsigned long long below = (1ull << lane) - 1ull;
#pragma unroll
    for (int ee = 0; ee < NEXP; ee++) {
        unsigned long long m = __ballot(e == ee);
        if (ee == e) rank = __popcll(m & below);
    }
    int pos = start[blockIdx.x * NEXP + e] + rank;
    perm[pos] = t;
    gatebuf[pos] = g;
    rowbuf[a] = pos;
}

// ================= grouped GEMM (R4 geometry): BM=256 x BN=128, BK=32, 8 waves =========
// Tri-buffer LDS (72 KB -> 2 blocks/CU), counted vmcnt 6/3/0, pre-swizzled source +
// swizzled ds_read (conflict-free, verified 0 conflicts R4). GATHER mode (GEMM1):
// A-tile rows fetched via perm[] indirection directly from the unpermuted bf16 xb
// using per-lane global source addresses -> pack kernel eliminated.
template <bool RELU, bool GATE, bool GATHER, int K, int N>
__global__ __launch_bounds__(512, 4) void moe_gemm_p(
    const bf16* __restrict__ A, const bf16* __restrict__ B,
    const float* __restrict__ bias, const float* __restrict__ gates,
    bf16* __restrict__ out, const int* __restrict__ cnt,
    const int* __restrict__ offs, const int* __restrict__ tile_e2,
    const int* __restrict__ tile_m2, const int* __restrict__ ntiles2,
    const int* __restrict__ perm) {
    constexpr int NT = N / 128;
    constexpr int nk = K / 32;
    int ntl = ntiles2[0];
    int nact = ntl * NT;
    int f = blockIdx.x;
    if (f >= nact) return;
    // bijective chunked XCD swizzle over the active range (m204)
    int q8 = nact >> 3, r8 = nact & 7;
    int xcd = f & 7, rest = f >> 3;
    int wg = (xcd < r8) ? (xcd * (q8 + 1) + rest)
                        : (r8 * (q8 + 1) + (xcd - r8) * q8 + rest);
    int tile = wg / NT, ncol = wg - tile * NT;
    int e = tile_e2[tile];
    int n_cnt = cnt[e];
    int off_e = offs[e];
    int m0 = tile_m2[tile] * 256;
    int n0 = ncol * 128;

    __shared__ bf16 As[3][256][32];  // 48 KB
    __shared__ bf16 Bs[3][128][32];  // 24 KB

    int tid = threadIdx.x;
    int lane = tid & 63;
    int wave = tid >> 6;   // 0..7
    int wm = wave & 1;     // A rows wm*128..+127
    int wn = wave >> 1;    // B rows wn*32..+31
    int quad = lane >> 4, l16 = lane & 15;
    int rsw = (quad ^ ((l16 >> 1) & 3)) * 8;  // swizzled 16B seg (elems)

    const bf16* Be = B + (size_t)e * (size_t)N * K;

    // staging: chunk c covers LDS row c>>2 (64B rows), seg c&3; source column
    // pre-swizzled by (row>>1)&3 == (tid>>3)&3 for all our row bases.
    int r0s = tid >> 2;  // 0..127
    int segs = (tid & 3) ^ ((tid >> 3) & 3);
    const bf16* agA0;
    const bf16* agA1;
    if (GATHER) {
        int g0 = off_e + m0 + r0s;
        int g1 = off_e + m0 + 128 + r0s;
        g0 = g0 < NASSIGN ? g0 : NASSIGN - 1;
        g1 = g1 < NASSIGN ? g1 : NASSIGN - 1;
        agA0 = A + (size_t)perm[g0] * K + segs * 8;
        agA1 = A + (size_t)perm[g1] * K + segs * 8;
    } else {
        const bf16* Ae = A + (size_t)off_e * K;
        agA0 = Ae + (size_t)(m0 + r0s) * K + segs * 8;
        agA1 = Ae + (size_t)(m0 + 128 + r0s) * K + segs * 8;
    }
    const bf16* bgB0 = Be + (size_t)(n0 + r0s) * K + segs * 8;

    auto STG = [&](int buf, int kt) {
        bf16* Ab = (bf16*)As + (size_t)buf * (256 * 32);
        bf16* Bb = (bf16*)Bs + (size_t)buf * (128 * 32);
        gload_lds16(agA0 + (size_t)kt * 32, Ab + (wave * 64) * 8);
        gload_lds16(agA1 + (size_t)kt * 32, Ab + (512 + wave * 64) * 8);
        gload_lds16(bgB0 + (size_t)kt * 32, Bb + (wave * 64) * 8);
    };

    f32x4 acc[8][2];
#pragma unroll
    for (int i = 0; i < 8; i++)
#pragma unroll
        for (int j = 0; j < 2; j++) acc[i][j] = f32x4{0.f, 0.f, 0.f, 0.f};

    // prologue: stage tiles 0,1 (3 loads each)
    STG(0, 0);
    STG(1, 1);

    int b = 0, bs = 2;  // compute buf, stage buf (t+2)%3
    for (int t = 0; t < nk; t++) {
        if (t + 2 < nk) {
            STG(bs, t + 2);
            asm volatile("s_waitcnt vmcnt(6)" ::: "memory");  // tile t landed
        } else if (t + 2 == nk) {
            asm volatile("s_waitcnt vmcnt(3)" ::: "memory");
        } else {
            asm volatile("s_waitcnt vmcnt(0)" ::: "memory");
        }
        asm volatile("s_barrier" ::: "memory");

        const bf16* Ab = (const bf16*)As + (size_t)b * (256 * 32);
        const bf16* Bb = (const bf16*)Bs + (size_t)b * (128 * 32);
        bf16x8 bf0 = *(const bf16x8*)(Bb + (wn * 32 + 0 * 16 + l16) * 32 + rsw);
        bf16x8 bf1 = *(const bf16x8*)(Bb + (wn * 32 + 1 * 16 + l16) * 32 + rsw);
        bf16x8 af[4];
#pragma unroll
        for (int mi = 0; mi < 4; mi++)
            af[mi] = *(const bf16x8*)(Ab + (wm * 128 + mi * 16 + l16) * 32 + rsw);
        asm volatile("s_waitcnt lgkmcnt(0)" ::: "memory");
        __builtin_amdgcn_s_setprio(1);
#pragma unroll
        for (int mi = 0; mi < 4; mi++) {
            acc[mi][0] = __builtin_amdgcn_mfma_f32_16x16x32_bf16(af[mi], bf0, acc[mi][0], 0, 0, 0);
            acc[mi][1] = __builtin_amdgcn_mfma_f32_16x16x32_bf16(af[mi], bf1, acc[mi][1], 0, 0, 0);
        }
        __builtin_amdgcn_s_setprio(0);
#pragma unroll
        for (int mi = 0; mi < 4; mi++)
            af[mi] = *(const bf16x8*)(Ab + (wm * 128 + (4 + mi) * 16 + l16) * 32 + rsw);
        asm volatile("s_waitcnt lgkmcnt(0)" ::: "memory");
        __builtin_amdgcn_s_setprio(1);
#pragma unroll
        for (int mi = 0; mi < 4; mi++) {
            acc[4 + mi][0] = __builtin_amdgcn_mfma_f32_16x16x32_bf16(af[mi], bf0, acc[4 + mi][0], 0, 0, 0);
            acc[4 + mi][1] = __builtin_amdgcn_mfma_f32_16x16x32_bf16(af[mi], bf1, acc[4 + mi][1], 0, 0, 0);
        }
        __builtin_amdgcn_s_setprio(0);
        asm volatile("s_barrier" ::: "memory");

        b = (b == 2) ? 0 : b + 1;
        bs = (bs == 2) ? 0 : bs + 1;
    }

#pragma unroll
    for (int mi = 0; mi < 8; mi++)
#pragma unroll
        for (int nj = 0; nj < 2; nj++)
#pragma unroll
            for (int r = 0; r < 4; r++) {
                int m = m0 + wm * 128 + mi * 16 + quad * 4 + r;
                if (m < n_cnt) {
                    int n = n0 + wn * 32 + nj * 16 + l16;
                    float v = acc[mi][nj][r] + bias[e * N + n];
                    if (RELU) v = v > 0.f ? v : 0.f;
                    if (GATE) v *= gates[off_e + m];
                    out[(size_t)(off_e + m) * N + n] = (bf16)v;
                }
            }
}

// ---------------- combine: bf16x8 per thread ----------------
__global__ __launch_bounds__(256) void combine_kernel(
    const bf16* __restrict__ eout, const int* __restrict__ rowbuf,
    float* __restrict__ out) {
    int c = blockIdx.x * 256 + threadIdx.x;  // chunk of 8 elems
    int t = c >> 7;
    int n = (c & 127) * 8;
    int r0 = rowbuf[2 * t], r1 = rowbuf[2 * t + 1];
    const bf16* p0 = eout + (size_t)r0 * HDIM + n;
    const bf16* p1 = eout + (size_t)r1 * HDIM + n;
    bf16x8 a = *(const bf16x8*)p0;
    bf16x8 b = *(const bf16x8*)p1;
    float* o = out + (size_t)t * HDIM + n;
    float4 v0 = {(float)a[0] + (float)b[0], (float)a[1] + (float)b[1],
                 (float)a[2] + (float)b[2], (float)a[3] + (float)b[3]};
    float4 v1 = {(float)a[4] + (float)b[4], (float)a[5] + (float)b[5],
                 (float)a[6] + (float)b[6], (float)a[7] + (float)b[7]};
    *(float4*)o = v0;
    *(float4*)(o + 4) = v1;
}

extern "C" void kernel_launch(void* const* d_in, const int* in_sizes, int n_in,
                              void* d_out, int out_size, void* d_ws, size_t ws_size,
                              hipStream_t stream) {
    const float* x = (const float*)d_in[0];
    const float* rw = (const float*)d_in[1];
    const float* rb = (const float*)d_in[2];
    const float* w1 = (const float*)d_in[3];
    const float* b1 = (const float*)d_in[4];
    const float* w2 = (const float*)d_in[5];
    const float* b2 = (const float*)d_in[6];
    float* out = (float*)d_out;

    char* ws = (char*)d_ws;
    size_t o = 0;
    auto alloc = [&](size_t bytes) {
        char* p = ws + o;
        o += (bytes + 255) & ~(size_t)255;
        return p;
    };
    bf16* w1t = (bf16*)alloc((size_t)NEXP * FDIM * HDIM * 2);
    bf16* w2t = (bf16*)alloc((size_t)NEXP * HDIM * FDIM * 2);
    bf16* hbuf = (bf16*)alloc((size_t)ROWCAP * FDIM * 2);
    bf16* eout = (bf16*)alloc((size_t)ROWCAP * HDIM * 2);
    bf16* xb = (bf16*)alloc((size_t)T_TOK * HDIM * 2);  // unpermuted bf16 x
    int* expert_pair = (int*)alloc((size_t)T_TOK * 4);
    float2* gate_pair = (float2*)alloc((size_t)T_TOK * 8);
    int* hist = (int*)alloc((size_t)NHB * NEXP * 4);
    int* start = (int*)alloc((size_t)NHB * NEXP * 4);
    int* perm = (int*)alloc((size_t)NASSIGN * 4);
    float* gatebuf = (float*)alloc((size_t)NASSIGN * 4);
    int* rowbuf = (int*)alloc((size_t)NASSIGN * 4);
    int* cnt = (int*)alloc(256);
    int* offs = (int*)alloc(256);
    int* tile_e2 = (int*)alloc((size_t)MAXT2 * 4);
    int* tile_m2 = (int*)alloc((size_t)MAXT2 * 4);
    int* ntiles2 = (int*)alloc(256);

    transpose_to_bf16<<<dim3(FDIM / 64, HDIM / 64, NEXP), 256, 0, stream>>>(w1, w1t, HDIM, FDIM);
    transpose_to_bf16<<<dim3(HDIM / 64, FDIM / 64, NEXP), 256, 0, stream>>>(w2, w2t, FDIM, HDIM);
    router_kernel<<<NHB, 256, 0, stream>>>(x, rw, rb, expert_pair, gate_pair, xb, hist);
    scan_kernel<<<1, 256, 0, stream>>>(hist, start, cnt, offs, tile_e2, tile_m2, ntiles2);
    scatter_kernel<<<NHB, 64, 0, stream>>>(expert_pair, gate_pair, start, perm, gatebuf, rowbuf);
    moe_gemm_p<true, false, true, HDIM, FDIM><<<dim3(MAXT2 * (FDIM / 128)), 512, 0, stream>>>(
        xb, w1t, b1, nullptr, hbuf, cnt, offs, tile_e2, tile_m2, ntiles2, perm);
    moe_gemm_p<false, true, false, FDIM, HDIM><<<dim3(MAXT2 * (HDIM / 128)), 512, 0, stream>>>(
        hbuf, w2t, b2, gatebuf, eout, cnt, offs, tile_e2, tile_m2, ntiles2, nullptr);
    combine_kernel<<<T_TOK * HDIM / 8 / 256, 256, 0, stream>>>(eout, rowbuf, out);
}